// Round 2
// baseline (129.766 us; speedup 1.0000x reference)
//
#include <hip/hip_runtime.h>
#include <cstdint>

typedef __bf16 bf16x8 __attribute__((ext_vector_type(8)));
typedef float f32x4 __attribute__((ext_vector_type(4)));
typedef unsigned short u16;

#define NROWS 4096
#define DIM 512
#define ZROWS 8192
#define BM 128
#define BK 64
#define NTILES 64    /* 8192/128 */
#define NBLOCKS 2080 /* 64*65/2 upper-triangular tile pairs */
#define CHUNK (NBLOCKS / 8) /* 260 — exact: 2080 % 8 == 0, swizzle bijective */

// ---------------- kernel 1: f32 -> bf16 + row norms (from bf16-rounded values) ----
__global__ __launch_bounds__(256) void prep_kernel(const float* __restrict__ lbl,
                                                   const float* __restrict__ pred,
                                                   u16* __restrict__ zb,
                                                   float* __restrict__ xnorm) {
    const int w = threadIdx.x >> 6;
    const int l = threadIdx.x & 63;
    const int row = blockIdx.x * 4 + w;
    const float* src = (row < NROWS) ? (lbl + (size_t)row * DIM)
                                     : (pred + (size_t)(row - NROWS) * DIM);
    const float4 v0 = *(const float4*)(src + l * 8);
    const float4 v1 = *(const float4*)(src + l * 8 + 4);
    float f[8] = {v0.x, v0.y, v0.z, v0.w, v1.x, v1.y, v1.z, v1.w};
    uint32_t pk[4];
    float nrm = 0.f;
#pragma unroll
    for (int j = 0; j < 4; ++j) {
        uint32_t b0 = __float_as_uint(f[2 * j]);
        uint32_t b1 = __float_as_uint(f[2 * j + 1]);
        uint32_t r0 = (b0 + 0x7fffu + ((b0 >> 16) & 1u)) >> 16;  // RNE to bf16
        uint32_t r1 = (b1 + 0x7fffu + ((b1 >> 16) & 1u)) >> 16;
        pk[j] = r0 | (r1 << 16);
        float fb0 = __uint_as_float(r0 << 16);
        float fb1 = __uint_as_float(r1 << 16);
        nrm += fb0 * fb0 + fb1 * fb1;
    }
    *(uint4*)(zb + (size_t)row * DIM + l * 8) = make_uint4(pk[0], pk[1], pk[2], pk[3]);
#pragma unroll
    for (int off = 32; off; off >>= 1) nrm += __shfl_xor(nrm, off);
    if (l == 0) xnorm[row] = nrm;
}

// ---------------- kernel 2: Z Z^T tile GEMM + fused exp/reduce epilogue -----------
// LDS exactly 32 KiB -> 5 blocks/CU; launch_bounds(256,5) keeps VGPR <= 102.
__global__ __launch_bounds__(256, 5) void mmd_gemm_kernel(const u16* __restrict__ zb,
                                                          const float* __restrict__ xnorm,
                                                          float* __restrict__ partials) {
    __shared__ u16 ldsA[BM * BK];  // [128][64] bf16, linear (global_load_lds dest)
    __shared__ u16 ldsB[BM * BK];

    // T1: XCD-aware swizzle — give each XCD a contiguous triangular range
    const int bid = (int)blockIdx.x;
    const int sbid = (bid & 7) * CHUNK + (bid >> 3);

    // decode upper-triangular (bm <= bn) tile pair
    int bm = 0, rem = sbid;
    while (rem >= (NTILES - bm)) { rem -= (NTILES - bm); ++bm; }
    const int bn = bm + rem;
    const bool diag = (bm == bn);

    const int tid = threadIdx.x;
    const int w = tid >> 6;
    const int l = tid & 63;
    const int warpM = w >> 1, warpN = w & 1;

    const int rowA0 = bm * BM;
    const int rowB0 = bn * BM;

    f32x4 acc[4][4];
#pragma unroll
    for (int m = 0; m < 4; ++m)
#pragma unroll
        for (int n = 0; n < 4; ++n) acc[m][n] = (f32x4){0.f, 0.f, 0.f, 0.f};

    for (int kt = 0; kt < DIM / BK; ++kt) {
        __syncthreads();  // previous compute done before overwriting LDS
#pragma unroll
        for (int it = 0; it < 4; ++it) {
            const int r = it * 32 + w * 8 + (l >> 3);
            const int cb = (l & 7) * 16;  // byte offset within 128B row-chunk
            const char* gA = (const char*)zb + ((size_t)(rowA0 + r) * DIM + kt * BK) * 2 + cb;
            char* lA = (char*)ldsA + it * 4096 + w * 1024 + l * 16;
            __builtin_amdgcn_global_load_lds((const __attribute__((address_space(1))) void*)gA,
                                             (__attribute__((address_space(3))) void*)lA, 16, 0, 0);
            if (!diag) {  // diagonal blocks: B tile == A tile, skip staging
                const char* gB = (const char*)zb + ((size_t)(rowB0 + r) * DIM + kt * BK) * 2 + cb;
                char* lB = (char*)ldsB + it * 4096 + w * 1024 + l * 16;
                __builtin_amdgcn_global_load_lds((const __attribute__((address_space(1))) void*)gB,
                                                 (__attribute__((address_space(3))) void*)lB, 16, 0, 0);
            }
        }
        __syncthreads();  // compiler drains vmcnt before barrier
        const char* ldsBr = diag ? (const char*)ldsA : (const char*)ldsB;
#pragma unroll
        for (int kk = 0; kk < 2; ++kk) {
            bf16x8 af[4], bg[4];
            const int kof = kk * 32 + (l >> 4) * 8;
#pragma unroll
            for (int m = 0; m < 4; ++m) {
                const int r = warpM * 64 + m * 16 + (l & 15);
                af[m] = *(const bf16x8*)((const char*)ldsA + r * 128 + kof * 2);
            }
#pragma unroll
            for (int n = 0; n < 4; ++n) {
                const int r = warpN * 64 + n * 16 + (l & 15);
                bg[n] = *(const bf16x8*)(ldsBr + r * 128 + kof * 2);
            }
#pragma unroll
            for (int m = 0; m < 4; ++m)
#pragma unroll
                for (int n = 0; n < 4; ++n)
                    acc[m][n] = __builtin_amdgcn_mfma_f32_16x16x32_bf16(af[m], bg[n], acc[m][n], 0, 0, 0);
        }
    }

    // epilogue: dist = xi + xj - 2*c ; term = exp(-dist/2) = exp2(-dist/(2 ln2))
    // signs are block-uniform (tiles never straddle the 4096 boundary).
    // provable skip: d > 40 => term < e^-20 = 2.1e-9 even summed over all pairs.
    const int baseI = rowA0 + warpM * 64;
    const int baseJ = rowB0 + warpN * 64;
    float4 xi4[4];
    float xj[4];
#pragma unroll
    for (int m = 0; m < 4; ++m)
        xi4[m] = *(const float4*)(xnorm + baseI + m * 16 + (l >> 4) * 4);
#pragma unroll
    for (int n = 0; n < 4; ++n) xj[n] = xnorm[baseJ + n * 16 + (l & 15)];

    float local = 0.f;
#pragma unroll
    for (int m = 0; m < 4; ++m)
#pragma unroll
        for (int n = 0; n < 4; ++n) {
            float d0 = (xi4[m].x + xj[n]) - 2.f * acc[m][n][0];
            float d1 = (xi4[m].y + xj[n]) - 2.f * acc[m][n][1];
            float d2 = (xi4[m].z + xj[n]) - 2.f * acc[m][n][2];
            float d3 = (xi4[m].w + xj[n]) - 2.f * acc[m][n][3];
            float dmin = fminf(fminf(d0, d1), fminf(d2, d3));
            if (dmin < 40.f) {
                local += exp2f(-0.72134752f * d0);
                local += exp2f(-0.72134752f * d1);
                local += exp2f(-0.72134752f * d2);
                local += exp2f(-0.72134752f * d3);
            }
        }
    const float sgn = ((bm < NROWS / BM) == (bn < NROWS / BM)) ? 1.f : -1.f;
    local *= sgn * (diag ? 1.f : 2.f);
#pragma unroll
    for (int off = 32; off; off >>= 1) local += __shfl_xor(local, off);
    __syncthreads();  // all LDS reads of ldsA done before reuse as scratch
    float* red = (float*)ldsA;
    if (l == 0) red[w] = local;
    __syncthreads();
    if (tid == 0) partials[sbid] = red[0] + red[1] + red[2] + red[3];
}

// ---------------- kernel 3: deterministic final reduce ---------------------------
__global__ __launch_bounds__(256) void reduce_kernel(const float* __restrict__ partials,
                                                     float* __restrict__ out, int n) {
    __shared__ float red[4];
    float s = 0.f;
    for (int i = threadIdx.x; i < n; i += 256) s += partials[i];
#pragma unroll
    for (int off = 32; off; off >>= 1) s += __shfl_xor(s, off);
    if ((threadIdx.x & 63) == 0) red[threadIdx.x >> 6] = s;
    __syncthreads();
    if (threadIdx.x == 0)
        out[0] = (red[0] + red[1] + red[2] + red[3]) * (1.f / 16777216.f);  // / 4096^2
}

extern "C" void kernel_launch(void* const* d_in, const int* in_sizes, int n_in,
                              void* d_out, int out_size, void* d_ws, size_t ws_size,
                              hipStream_t stream) {
    const float* lbl = (const float*)d_in[0];
    const float* pred = (const float*)d_in[1];
    u16* zb = (u16*)d_ws;
    float* xnorm = (float*)((char*)d_ws + (size_t)ZROWS * DIM * 2);
    float* partials = (float*)((char*)d_ws + (size_t)ZROWS * DIM * 2 + (size_t)ZROWS * 4);

    prep_kernel<<<ZROWS / 4, 256, 0, stream>>>(lbl, pred, zb, xnorm);
    mmd_gemm_kernel<<<NBLOCKS, 256, 0, stream>>>(zb, xnorm, partials);
    reduce_kernel<<<1, 256, 0, stream>>>(partials, (float*)d_out, NBLOCKS);
}

// Round 3
// 61.233 us; speedup vs baseline: 2.1192x; 2.1192x over previous
//
#include <hip/hip_runtime.h>
#include <cstdint>

typedef __bf16 bf16x8 __attribute__((ext_vector_type(8)));
typedef float f32x4 __attribute__((ext_vector_type(4)));
typedef unsigned short u16;

#define NROWS 4096
#define DIM 512
#define ZROWS 8192
#define BM 128
#define BK 32
#define NKT 16       /* DIM/BK */
#define NTILES 64    /* 8192/128 */
#define NBLOCKS 2080 /* 64*65/2 upper-triangular tile pairs */
#define CHUNK (NBLOCKS / 8) /* 260 — exact: 2080 % 8 == 0, swizzle bijective */

// ---------------- kernel 1: f32 -> bf16 + row norms (from bf16-rounded values) ----
__global__ __launch_bounds__(256) void prep_kernel(const float* __restrict__ lbl,
                                                   const float* __restrict__ pred,
                                                   u16* __restrict__ zb,
                                                   float* __restrict__ xnorm) {
    const int w = threadIdx.x >> 6;
    const int l = threadIdx.x & 63;
    const int row = blockIdx.x * 4 + w;
    const float* src = (row < NROWS) ? (lbl + (size_t)row * DIM)
                                     : (pred + (size_t)(row - NROWS) * DIM);
    const float4 v0 = *(const float4*)(src + l * 8);
    const float4 v1 = *(const float4*)(src + l * 8 + 4);
    float f[8] = {v0.x, v0.y, v0.z, v0.w, v1.x, v1.y, v1.z, v1.w};
    uint32_t pk[4];
    float nrm = 0.f;
#pragma unroll
    for (int j = 0; j < 4; ++j) {
        uint32_t b0 = __float_as_uint(f[2 * j]);
        uint32_t b1 = __float_as_uint(f[2 * j + 1]);
        uint32_t r0 = (b0 + 0x7fffu + ((b0 >> 16) & 1u)) >> 16;  // RNE to bf16
        uint32_t r1 = (b1 + 0x7fffu + ((b1 >> 16) & 1u)) >> 16;
        pk[j] = r0 | (r1 << 16);
        float fb0 = __uint_as_float(r0 << 16);
        float fb1 = __uint_as_float(r1 << 16);
        nrm += fb0 * fb0 + fb1 * fb1;
    }
    *(uint4*)(zb + (size_t)row * DIM + l * 8) = make_uint4(pk[0], pk[1], pk[2], pk[3]);
#pragma unroll
    for (int off = 32; off; off >>= 1) nrm += __shfl_xor(nrm, off);
    if (l == 0) xnorm[row] = nrm;
}

// ---------------- kernel 2: Z Z^T tile GEMM + fused exp/reduce epilogue -----------
// 2-phase prefetch (T3-minimum): stage(t+1) issued BEFORE compute(t); one barrier
// per K-step. LDS = 2 dbuf x {A,B} x 128x32 bf16 = exactly 32 KiB.
// LDS swizzle: 16B slot ^= ((row&3)<<4), applied on BOTH global source (stage)
// and ds_read (rule #21) -> 16-way bank conflict reduced to 4-way.
__global__ __launch_bounds__(256) void mmd_gemm_kernel(const u16* __restrict__ zb,
                                                       const float* __restrict__ xnorm,
                                                       float* __restrict__ partials) {
    __shared__ u16 lds[2][2][BM * BK];  // [dbuf][A/B][128*32]

    // T1: XCD-aware swizzle — give each XCD a contiguous triangular range
    const int bid = (int)blockIdx.x;
    const int sbid = (bid & 7) * CHUNK + (bid >> 3);

    // decode upper-triangular (bm <= bn) tile pair
    int bm = 0, rem = sbid;
    while (rem >= (NTILES - bm)) { rem -= (NTILES - bm); ++bm; }
    const int bn = bm + rem;
    const bool diag = (bm == bn);

    const int tid = threadIdx.x;
    const int w = tid >> 6;
    const int l = tid & 63;
    const int warpM = w >> 1, warpN = w & 1;

    const char* zbytes = (const char*)zb;
    const size_t rowA0 = (size_t)bm * BM;
    const size_t rowB0 = (size_t)bn * BM;

    f32x4 acc[4][4];
#pragma unroll
    for (int m = 0; m < 4; ++m)
#pragma unroll
        for (int n = 0; n < 4; ++n) acc[m][n] = (f32x4){0.f, 0.f, 0.f, 0.f};

    // --- staging: tile kt (64B column chunk) into lds[b][*] ---
    auto STAGE = [&](int b, int kt) {
#pragma unroll
        for (int it = 0; it < 2; ++it) {
            const int r = it * 64 + w * 16 + (l >> 2);       // LDS row
            const int cb = (l & 3) * 16;                     // LDS 16B slot
            const int csrc = cb ^ ((r & 3) << 4);            // pre-swizzled source slot
            const char* gA = zbytes + (rowA0 + r) * (DIM * 2) + kt * 64 + csrc;
            char* lA = (char*)&lds[b][0][0] + it * 4096 + w * 1024 + l * 16;
            __builtin_amdgcn_global_load_lds((const __attribute__((address_space(1))) void*)gA,
                                             (__attribute__((address_space(3))) void*)lA, 16, 0, 0);
            if (!diag) {
                const char* gB = zbytes + (rowB0 + r) * (DIM * 2) + kt * 64 + csrc;
                char* lB = (char*)&lds[b][1][0] + it * 4096 + w * 1024 + l * 16;
                __builtin_amdgcn_global_load_lds((const __attribute__((address_space(1))) void*)gB,
                                                 (__attribute__((address_space(3))) void*)lB, 16, 0, 0);
            }
        }
    };

    // --- compute one K-step from lds[b] ---
    const int klane = ((l >> 4) * 16) ^ ((l & 3) << 4);  // k-slice byte, read-side swizzle
    auto COMPUTE = [&](int b) {
        const char* abase = (const char*)&lds[b][0][0];
        const char* bbase = diag ? abase : (const char*)&lds[b][1][0];
        bf16x8 af[4], bg[4];
#pragma unroll
        for (int m = 0; m < 4; ++m) {
            const int rr = warpM * 64 + m * 16 + (l & 15);
            af[m] = *(const bf16x8*)(abase + rr * 64 + klane);
        }
#pragma unroll
        for (int n = 0; n < 4; ++n) {
            const int rr = warpN * 64 + n * 16 + (l & 15);
            bg[n] = *(const bf16x8*)(bbase + rr * 64 + klane);
        }
#pragma unroll
        for (int m = 0; m < 4; ++m)
#pragma unroll
            for (int n = 0; n < 4; ++n)
                acc[m][n] = __builtin_amdgcn_mfma_f32_16x16x32_bf16(af[m], bg[n], acc[m][n], 0, 0, 0);
    };

    STAGE(0, 0);
    __syncthreads();  // drains vmcnt: tile 0 resident
    for (int kt = 0; kt < NKT; kt += 2) {
        STAGE(1, kt + 1);     // prefetch next while computing current
        COMPUTE(0);
        __syncthreads();      // drains vmcnt (tile kt+1 in) + all reads of buf0 done
        if (kt + 2 < NKT) STAGE(0, kt + 2);
        COMPUTE(1);
        __syncthreads();
    }

    // epilogue: dist = xi + xj - 2*c ; term = exp(-dist/2) = exp2(-dist/(2 ln2))
    // signs are block-uniform (tiles never straddle the 4096 boundary).
    // provable skip: d > 40 => term < e^-20 = 2.1e-9 even summed over all pairs.
    const int baseI = (int)rowA0 + warpM * 64;
    const int baseJ = (int)rowB0 + warpN * 64;
    float4 xi4[4];
    float xj[4];
#pragma unroll
    for (int m = 0; m < 4; ++m)
        xi4[m] = *(const float4*)(xnorm + baseI + m * 16 + (l >> 4) * 4);
#pragma unroll
    for (int n = 0; n < 4; ++n) xj[n] = xnorm[baseJ + n * 16 + (l & 15)];

    float local = 0.f;
#pragma unroll
    for (int m = 0; m < 4; ++m)
#pragma unroll
        for (int n = 0; n < 4; ++n) {
            float d0 = (xi4[m].x + xj[n]) - 2.f * acc[m][n][0];
            float d1 = (xi4[m].y + xj[n]) - 2.f * acc[m][n][1];
            float d2 = (xi4[m].z + xj[n]) - 2.f * acc[m][n][2];
            float d3 = (xi4[m].w + xj[n]) - 2.f * acc[m][n][3];
            float dmin = fminf(fminf(d0, d1), fminf(d2, d3));
            if (dmin < 40.f) {
                local += exp2f(-0.72134752f * d0);
                local += exp2f(-0.72134752f * d1);
                local += exp2f(-0.72134752f * d2);
                local += exp2f(-0.72134752f * d3);
            }
        }
    const float sgn = ((bm < NROWS / BM) == (bn < NROWS / BM)) ? 1.f : -1.f;
    local *= sgn * (diag ? 1.f : 2.f);
#pragma unroll
    for (int off = 32; off; off >>= 1) local += __shfl_xor(local, off);
    // loop's final __syncthreads() already separated all LDS reads; reuse as scratch
    float* red = (float*)&lds[0][0][0];
    if (l == 0) red[w] = local;
    __syncthreads();
    if (tid == 0) partials[sbid] = red[0] + red[1] + red[2] + red[3];
}

// ---------------- kernel 3: deterministic final reduce ---------------------------
__global__ __launch_bounds__(256) void reduce_kernel(const float* __restrict__ partials,
                                                     float* __restrict__ out, int n) {
    __shared__ float red[4];
    float s = 0.f;
    for (int i = threadIdx.x; i < n; i += 256) s += partials[i];
#pragma unroll
    for (int off = 32; off; off >>= 1) s += __shfl_xor(s, off);
    if ((threadIdx.x & 63) == 0) red[threadIdx.x >> 6] = s;
    __syncthreads();
    if (threadIdx.x == 0)
        out[0] = (red[0] + red[1] + red[2] + red[3]) * (1.f / 16777216.f);  // / 4096^2
}

extern "C" void kernel_launch(void* const* d_in, const int* in_sizes, int n_in,
                              void* d_out, int out_size, void* d_ws, size_t ws_size,
                              hipStream_t stream) {
    const float* lbl = (const float*)d_in[0];
    const float* pred = (const float*)d_in[1];
    u16* zb = (u16*)d_ws;
    float* xnorm = (float*)((char*)d_ws + (size_t)ZROWS * DIM * 2);
    float* partials = (float*)((char*)d_ws + (size_t)ZROWS * DIM * 2 + (size_t)ZROWS * 4);

    prep_kernel<<<ZROWS / 4, 256, 0, stream>>>(lbl, pred, zb, xnorm);
    mmd_gemm_kernel<<<NBLOCKS, 256, 0, stream>>>(zb, xnorm, partials);
    reduce_kernel<<<1, 256, 0, stream>>>(partials, (float*)d_out, NBLOCKS);
}